// Round 5
// baseline (237.665 us; speedup 1.0000x reference)
//
#include <hip/hip_runtime.h>
#include <hip/hip_bf16.h>

// SNN IF scan, T=4. Memory-bound: 134 MB in + 134 MB out (~43 us HBM floor,
// less with LLC-resident input). History: R0/R2 serialized loads = 82 us;
// R4 forced 16-deep load batch + phase-separated stores = ~70 us.
// R5: software pipeline — prefetch group u+1 (4 loads) BEFORE compute+store
// of group u, so stores interleave with outstanding loads (copy-kernel-style
// steady R/W mix, progressive vmcnt instead of one bulk wait). Loads are
// plain (LLC-friendly: restore-copy leaves ~half of x resident); stores nt
// (output never re-read, don't evict x).

#define T_STEPS 4
#define UNROLL 4

typedef float vfloat4 __attribute__((ext_vector_type(4)));

__global__ __launch_bounds__(256) void IF_18622978195596_kernel(
    const vfloat4* __restrict__ x, const float* __restrict__ thresh_p,
    vfloat4* __restrict__ out, int n4) {
    // n4 = 2^21 divides exactly by 256*UNROLL; no guards needed.
    const int base = blockIdx.x * (256 * UNROLL) + threadIdx.x;
    const float th = *thresh_p;

    // prologue: group 0 in flight
    vfloat4 cur[T_STEPS];
#pragma unroll
    for (int t = 0; t < T_STEPS; ++t)
        cur[t] = x[(size_t)t * n4 + base];

#pragma unroll
    for (int u = 0; u < UNROLL; ++u) {
        vfloat4 nxt[T_STEPS];
        if (u + 1 < UNROLL) {
            const int ip = base + (u + 1) * 256;
#pragma unroll
            for (int t = 0; t < T_STEPS; ++t)
                nxt[t] = x[(size_t)t * n4 + ip];
        }
        // keep the prefetch above the consume of cur (vmcnt wait lands here)
        __builtin_amdgcn_sched_barrier(0);

        const int i = base + u * 256;
        vfloat4 mem = {0.5f * th, 0.5f * th, 0.5f * th, 0.5f * th};
#pragma unroll
        for (int t = 0; t < T_STEPS; ++t) {
            mem += cur[t];
            vfloat4 s;
            s.x = (mem.x >= th) ? th : 0.0f;
            s.y = (mem.y >= th) ? th : 0.0f;
            s.z = (mem.z >= th) ? th : 0.0f;
            s.w = (mem.w >= th) ? th : 0.0f;
            mem -= s;
            __builtin_nontemporal_store(s, &out[(size_t)t * n4 + i]);
        }
        if (u + 1 < UNROLL) {
#pragma unroll
            for (int t = 0; t < T_STEPS; ++t) cur[t] = nxt[t];
        }
    }
}

extern "C" void kernel_launch(void* const* d_in, const int* in_sizes, int n_in,
                              void* d_out, int out_size, void* d_ws, size_t ws_size,
                              hipStream_t stream) {
    const float* x = (const float*)d_in[0];
    const float* thresh = (const float*)d_in[1];
    float* out = (float*)d_out;

    int total = in_sizes[0];              // 33,554,432 floats
    int n_per_t = total / T_STEPS;        // 8,388,608 neurons
    int n4 = n_per_t / 4;                 // 2,097,152 vfloat4 per timestep

    int block = 256;
    int per_block = block * UNROLL;       // 1024 vfloat4 per block per t
    int grid = n4 / per_block;            // 2048 blocks (exact)
    IF_18622978195596_kernel<<<grid, block, 0, stream>>>(
        (const vfloat4*)x, thresh, (vfloat4*)out, n4);
}

// Round 6
// 221.641 us; speedup vs baseline: 1.0723x; 1.0723x over previous
//
#include <hip/hip_runtime.h>
#include <hip/hip_bf16.h>

// SNN IF scan, T=4. Memory-bound: 134 MB in + 134 MB out (~43 us floor at
// copy rate). History: serialized loads (R0/R2/R5, VGPR<=32) = ~82 us;
// R4's forced 16-deep nt batch = ~70 us. Deep bulk issue is the only lever
// that has moved the needle.
// R6 = R4 scaled + fixed: 8 groups x 4 timesteps = 32 nt loads, issued
// U-MAJOR (consume order!) so the consume phase drains progressively
// (vmcnt(28)->(24)->...), overlapping each group's stores with the
// remaining in-flight loads — instead of R4's t-major issue which forced a
// near-total vmcnt(3) bulk wait before the first consume.
// sched_barrier(0) pins the batch (stops the scheduler collapsing it; R2/R5
// were silently re-serialized — VGPR_Count >= ~130 verifies it survived).

#define T_STEPS 4
#define UNROLL 8

typedef float vfloat4 __attribute__((ext_vector_type(4)));

__global__ __launch_bounds__(256) void IF_18622978195596_kernel(
    const vfloat4* __restrict__ x, const float* __restrict__ thresh_p,
    vfloat4* __restrict__ out, int n4) {
    // n4 = 2^21 divides exactly by 256*UNROLL = 2048; no guards.
    const int base = blockIdx.x * (256 * UNROLL) + threadIdx.x;
    const float th = *thresh_p;

    // ---- load phase: 32 independent nt loads, issued in consume order ----
    vfloat4 xv[UNROLL][T_STEPS];
#pragma unroll
    for (int u = 0; u < UNROLL; ++u) {
        const int i = base + u * 256;
#pragma unroll
        for (int t = 0; t < T_STEPS; ++t) {
            xv[u][t] = __builtin_nontemporal_load(&x[(size_t)t * n4 + i]);
        }
    }
    // pin the batch: nothing crosses this point
    __builtin_amdgcn_sched_barrier(0);

    // ---- consume phase, in issue order -> progressive vmcnt drain ----
#pragma unroll
    for (int u = 0; u < UNROLL; ++u) {
        const int i = base + u * 256;
        vfloat4 mem = {0.5f * th, 0.5f * th, 0.5f * th, 0.5f * th};
#pragma unroll
        for (int t = 0; t < T_STEPS; ++t) {
            mem += xv[u][t];
            vfloat4 s;
            s.x = (mem.x >= th) ? th : 0.0f;
            s.y = (mem.y >= th) ? th : 0.0f;
            s.z = (mem.z >= th) ? th : 0.0f;
            s.w = (mem.w >= th) ? th : 0.0f;
            mem -= s;
            __builtin_nontemporal_store(s, &out[(size_t)t * n4 + i]);
        }
    }
}

extern "C" void kernel_launch(void* const* d_in, const int* in_sizes, int n_in,
                              void* d_out, int out_size, void* d_ws, size_t ws_size,
                              hipStream_t stream) {
    const float* x = (const float*)d_in[0];
    const float* thresh = (const float*)d_in[1];
    float* out = (float*)d_out;

    int total = in_sizes[0];              // 33,554,432 floats
    int n_per_t = total / T_STEPS;        // 8,388,608 neurons
    int n4 = n_per_t / 4;                 // 2,097,152 vfloat4 per timestep

    int block = 256;
    int per_block = block * UNROLL;       // 2048 vfloat4 per block per t
    int grid = n4 / per_block;            // 1024 blocks = 4 per CU, exact
    IF_18622978195596_kernel<<<grid, block, 0, stream>>>(
        (const vfloat4*)x, thresh, (vfloat4*)out, n4);
}